// Round 6
// baseline (2212.911 us; speedup 1.0000x reference)
//
#include <hip/hip_runtime.h>

// Problem dims (fixed by setup_inputs)
constexpr int NB = 1024;   // batch
constexpr int NT = 512;    // time steps
constexpr int NI = 100;    // input dim
constexpr int NH = 150;    // hidden dim
constexpr int NO = 3;      // output classes

// DPP-based add: v += shuffled(v).
// 0xB1 quad_perm xor1 | 0x4E quad_perm xor2 | 0x141 row_half_mirror (completes 8-sum)
// 0x140 row_mirror (completes 16-sum)
template<int CTRL>
__device__ __forceinline__ float dpp_add(float v) {
    int t = __builtin_amdgcn_update_dpp(0, __float_as_int(v), CTRL, 0xF, 0xF, true);
    return v + __int_as_float(t);
}

// ================= Kernel 1: xw[t][b][h] = sum_i x[b,t,i] * Wih[h,i] =============
// Block: 256 thr = (128 b-rows) x (2 wave-uniform h-groups of 16). x-tile in LDS;
// Wih rows via wave-uniform pointers (scalarizable to s_load); 64 FMA per LDS read.
// Output layout [T][B][H]: at fixed t the 128-row tile is one contiguous region.
constexpr int GB = 128, GH = 32, GT = 256;
__global__ __launch_bounds__(GT, 2)
void xw_gemm(const float* __restrict__ x, const float* __restrict__ Wih,
             float* __restrict__ xw)
{
    __shared__ __align__(16) float xt[GB * NI];   // 51.2 KB
    __shared__ __align__(16) float ot[GB * GH];   // 16 KB
    const int tid = threadIdx.x;
    const int b0 = blockIdx.x * GB, t = blockIdx.y, h0 = blockIdx.z * GH;

    for (int e = tid; e < GB * (NI / 4); e += GT) {
        int r = e / 25, c = e - r * 25;
        reinterpret_cast<float4*>(xt)[r * 25 + c] =
            reinterpret_cast<const float4*>(x + ((size_t)(b0 + r) * NT + t) * NI)[c];
    }
    __syncthreads();

    const int row = tid & (GB - 1);
    const int hbase = __builtin_amdgcn_readfirstlane(h0 + (tid >> 7) * 16);  // wave-uniform
    const float* wrow[16];
#pragma unroll
    for (int j = 0; j < 16; ++j) {
        int h = hbase + j;
        wrow[j] = Wih + (size_t)(h < NH ? h : NH - 1) * NI;  // clamp OOB rows (unused)
    }
    float acc[16];
#pragma unroll
    for (int j = 0; j < 16; ++j) acc[j] = 0.f;

    const float4* xr = reinterpret_cast<const float4*>(xt) + row * 25;
#pragma unroll 5
    for (int k4 = 0; k4 < 25; ++k4) {
        const float4 xv = xr[k4];
#pragma unroll
        for (int j = 0; j < 16; ++j) {
            const float4 wv = reinterpret_cast<const float4*>(wrow[j])[k4];
            acc[j] += wv.x * xv.x;
            acc[j] += wv.y * xv.y;
            acc[j] += wv.z * xv.z;
            acc[j] += wv.w * xv.w;
        }
    }
    const int hg = (tid >> 7) * 16;
#pragma unroll
    for (int j = 0; j < 16; ++j) ot[row * GH + hg + j] = acc[j];
    __syncthreads();

    // coalesced float2 stores (row stride 150 floats: f4 misaligns on odd rows)
    for (int e = tid; e < GB * 16; e += GT) {
        int r = e >> 4, p = e & 15, h = h0 + 2 * p;
        if (h < NH) {
            float2 v = *reinterpret_cast<const float2*>(&ot[r * GH + 2 * p]);
            *reinterpret_cast<float2*>(&xw[((size_t)t * NB + b0 + r) * NH + h]) = v;
        }
    }
}

// ================= Kernel 2: recurrence h_t = relu(xw_t + h_{t-1} Whh^T) =========
// K = 160 (150 h + 10 zero-pad). Block 512 thr = 8 waves; kg = lane&7 (8 k-groups x
// 5 float4-chunks); oq = lane>>3; oi = wv*8+oq in [0,64); o-slots {oi, oi+64, oi+128}
// (o<150 -> h row, 150..152 -> fc rows, >=153 dead W=0). Wreg = 60 floats + 12 acc
// => fits the 128-VGPR cap with margin (R5 proved 80+10 fits at 120). ROWS=4, grid
// 256 = 1 block/CU (the only residency the HW gives us). 3-stage DPP reduce.
constexpr int KP2 = 160, ROWS2 = 4, NTH2 = 512;
__global__ __launch_bounds__(NTH2, 2)
void rnn_rec(const float* __restrict__ xw, const float* __restrict__ h0v,
             const float* __restrict__ g, const float* __restrict__ Whh,
             const float* __restrict__ Wfc, float* __restrict__ out,
             float* __restrict__ hidden, float* __restrict__ logits)
{
    __shared__ __align__(16) float hx[2][ROWS2 * KP2];  // 2 x 2.56 KB
    __shared__ float lg[2][ROWS2][4];

    const int tid = threadIdx.x, lane = tid & 63, wv = tid >> 6;
    const int kg = lane & 7, oq = lane >> 3, oi = wv * 8 + oq;
    const int row0 = blockIdx.x * ROWS2;

    // W slice: 3 o-slots x 5 chunks x 4 = 60 regs
    float Wreg[3][5][4];
#pragma unroll
    for (int j = 0; j < 3; ++j) {
        const int o = oi + 64 * j;
#pragma unroll
        for (int i = 0; i < 5; ++i)
#pragma unroll
            for (int q = 0; q < 4; ++q) {
                const int k = 4 * (kg + 8 * i) + q;
                float v = 0.f;
                if (k < NH) {
                    if (o < NH) v = Whh[o * NH + k];
                    else if (o < NH + NO) v = Wfc[(o - NH) * NH + k];
                }
                Wreg[j][i][q] = v;
            }
    }

    for (int e = tid; e < ROWS2 * NH; e += NTH2) {
        int b = e / NH, k = e - b * NH;
        hx[0][b * KP2 + k] = h0v[(row0 + b) * NH + k];
    }
    if (tid < 2 * ROWS2 * 10) {  // zero pads k in [150,160) in both buffers
        int u = tid, f = u / (ROWS2 * 10); u -= f * (ROWS2 * 10);
        int b = u / 10, z = u - b * 10;
        hx[f][b * KP2 + NH + z] = 0.f;
    }
    __syncthreads();

    const float* xwb = xw + (size_t)(row0 + (kg & 3)) * NH;          // + t*NB*NH per step
    float* hidb = hidden + (size_t)(row0 + (kg & 3)) * NT * NH;      // writers: kg<4
    const float* grow = g + (size_t)(row0 + (tid & 3)) * NT * NO;    // tid<4
    const size_t emitb = (size_t)(row0 + (tid & 3)) * NT * NO;       // tid<4

    auto stepf = [&](int t, const float* __restrict__ cur, float* __restrict__ nxt,
                     float (*__restrict__ lgb)[4]) {
        // prefetch xw[t] for this lane's h-outputs (hidden under the dot phase)
        float xwv[3] = {0.f, 0.f, 0.f};
        const bool wr = (kg < ROWS2);
        if (wr && t < NT) {
            const float* xp = xwb + (size_t)t * (NB * NH);
#pragma unroll
            for (int j = 0; j < 3; ++j) {
                const int o = oi + 64 * j;
                if (o < NH) xwv[j] = xp[o];
            }
        }
        float g0 = 0.f, g1 = 0.f, g2 = 0.f;
        const bool de = (tid < ROWS2) && (t >= 1);
        if (de) {
            const float* gp = grow + (size_t)(t - 1) * NO;
            g0 = gp[0]; g1 = gp[1]; g2 = gp[2];
        }

        const float4* cur4 = reinterpret_cast<const float4*>(cur) + kg;
        float acc[3][ROWS2];
#pragma unroll
        for (int j = 0; j < 3; ++j)
#pragma unroll
            for (int b = 0; b < ROWS2; ++b) acc[j][b] = 0.f;

#pragma unroll
        for (int i = 0; i < 5; ++i)
#pragma unroll
            for (int b = 0; b < ROWS2; ++b) {
                const float4 hv = cur4[b * (KP2 / 4) + 8 * i];
#pragma unroll
                for (int j = 0; j < 3; ++j) {
                    acc[j][b] += Wreg[j][i][0] * hv.x;
                    acc[j][b] += Wreg[j][i][1] * hv.y;
                    acc[j][b] += Wreg[j][i][2] * hv.z;
                    acc[j][b] += Wreg[j][i][3] * hv.w;
                }
            }

        // 3-stage DPP butterfly across the 8 k-groups
#pragma unroll
        for (int j = 0; j < 3; ++j)
#pragma unroll
            for (int b = 0; b < ROWS2; ++b) {
                float v = acc[j][b];
                v = dpp_add<0xB1>(v);   // xor 1
                v = dpp_add<0x4E>(v);   // xor 2
                v = dpp_add<0x141>(v);  // half mirror -> 8-sum
                acc[j][b] = v;
            }

        // phase B: lane kg==b writes row b
        if (wr) {
            const int b = kg;
#pragma unroll
            for (int j = 0; j < 3; ++j) {
                const int o = oi + 64 * j;
                if (o < NH) {
                    if (t < NT) {
                        float v = fmaxf(acc[j][b] + xwv[j], 0.f);
                        nxt[b * KP2 + o] = v;
                        hidb[(size_t)t * NH + o] = v;
                    }
                } else if (o < NH + NO) {
                    lgb[b][o - NH] = acc[j][b];
                }
            }
        }
        __syncthreads();

        if (de) {
            float l0 = lgb[tid][0], l1 = lgb[tid][1], l2 = lgb[tid][2];
            float s0 = l0 + g0, s1 = l1 + g1, s2 = l2 + g2;
            int am = 0; float best = s0;
            if (s1 > best) { best = s1; am = 1; }
            if (s2 > best) { am = 2; }
            size_t base = emitb + (size_t)(t - 1) * NO;
            out[base + 0] = (am == 0) ? 1.f : 0.f;
            out[base + 1] = (am == 1) ? 1.f : 0.f;
            out[base + 2] = (am == 2) ? 1.f : 0.f;
            logits[base + 0] = l0;
            logits[base + 1] = l1;
            logits[base + 2] = l2;
        }
    };

    for (int t = 0; t < NT; t += 2) {
        stepf(t,     hx[0], hx[1], lg[0]);
        stepf(t + 1, hx[1], hx[0], lg[1]);
    }
    stepf(NT, hx[0], hx[1], lg[0]);  // tail: fc of h[NT-1] + final emit
}

// ================= Fallback (R5 kernel verbatim) if d_ws is too small ============
namespace fb {
constexpr int KP = 256, XOFF = 152, ROWS = 2, KG = 16, NCH = 4, NJ = 5, NTH = 512;
__global__ __launch_bounds__(NTH, 2)
void rnn_fused(const float* __restrict__ x, const float* __restrict__ h0,
               const float* __restrict__ g, const float* __restrict__ Wih,
               const float* __restrict__ Whh, const float* __restrict__ Wfc,
               float* __restrict__ out, float* __restrict__ hidden,
               float* __restrict__ logits)
{
    __shared__ __align__(16) float hx[2][ROWS * KP];
    __shared__ float lg[2][ROWS][4];
    const int tid = threadIdx.x, lane = tid & 63, wv = tid >> 6;
    const int kg = lane & 15, oq = lane >> 4, oi = wv * 4 + oq;
    const int row0 = blockIdx.x * ROWS;
    float Wreg[NJ][NCH][4];
#pragma unroll
    for (int j = 0; j < NJ; ++j) {
        const int o = oi + 32 * j;
#pragma unroll
        for (int i = 0; i < NCH; ++i)
#pragma unroll
            for (int q = 0; q < 4; ++q) {
                const int k = 4 * (kg + KG * i) + q;
                float v = 0.f;
                if (o < NH) {
                    if (k < NH) v = Whh[o * NH + k];
                    else if (k >= XOFF && k < XOFF + NI) v = Wih[o * NI + (k - XOFF)];
                } else if (o < NH + NO) {
                    if (k < NH) v = Wfc[(o - NH) * NH + k];
                }
                Wreg[j][i][q] = v;
            }
    }
    for (int e = tid; e < ROWS * NH; e += NTH) {
        int b = e / NH, k = e - b * NH;
        hx[0][b * KP + k] = h0[(row0 + b) * NH + k];
    }
    for (int e = tid; e < ROWS * NI; e += NTH) {
        int b = e / NI, i = e - b * NI;
        hx[0][b * KP + XOFF + i] = x[((size_t)(row0 + b) * NT + 0) * NI + i];
    }
    if (tid < 2 * ROWS * 6) {
        int u = tid; int f = u / (ROWS * 6); u -= f * (ROWS * 6);
        int b = u / 6, z = u - b * 6;
        int k = (z < 2) ? (NH + z) : (252 + z - 2);
        hx[f][b * KP + k] = 0.f;
    }
    __syncthreads();
    const int xb = (tid / 25) & 1, xq = tid - (tid / 25) * 25;
    const float* xrow = x + ((size_t)(row0 + xb) * NT) * NI + 4 * xq;
    float* hidb = hidden + ((size_t)(row0 + (kg & 1)) * NT) * NH;
    const float* grow = g + ((size_t)(row0 + (tid & 1)) * NT) * NO;
    const size_t emitb = ((size_t)(row0 + (tid & 1)) * NT) * NO;
    auto stepf = [&](int t, const float* __restrict__ cur, float* __restrict__ nxt,
                     float (*__restrict__ lgb)[4]) {
        float4 xp = make_float4(0.f, 0.f, 0.f, 0.f);
        const bool do_x = (tid < 50) && (t < NT - 1);
        if (do_x) xp = *reinterpret_cast<const float4*>(xrow + (size_t)(t + 1) * NI);
        float g0 = 0.f, g1 = 0.f, g2 = 0.f;
        const bool do_e = (tid < ROWS) && (t >= 1);
        if (do_e) {
            const float* gp = grow + (size_t)(t - 1) * NO;
            g0 = gp[0]; g1 = gp[1]; g2 = gp[2];
        }
        const float4* cur4 = reinterpret_cast<const float4*>(cur) + kg;
        float acc[NJ][ROWS];
#pragma unroll
        for (int j = 0; j < NJ; ++j)
#pragma unroll
            for (int b = 0; b < ROWS; ++b) acc[j][b] = 0.f;
#pragma unroll
        for (int i = 0; i < NCH; ++i)
#pragma unroll
            for (int b = 0; b < ROWS; ++b) {
                const float4 hv = cur4[b * (KP / 4) + KG * i];
#pragma unroll
                for (int j = 0; j < NJ; ++j) {
                    acc[j][b] += Wreg[j][i][0] * hv.x;
                    acc[j][b] += Wreg[j][i][1] * hv.y;
                    acc[j][b] += Wreg[j][i][2] * hv.z;
                    acc[j][b] += Wreg[j][i][3] * hv.w;
                }
            }
#pragma unroll
        for (int j = 0; j < NJ; ++j)
#pragma unroll
            for (int b = 0; b < ROWS; ++b) {
                float v = acc[j][b];
                v = dpp_add<0xB1>(v);
                v = dpp_add<0x4E>(v);
                v = dpp_add<0x141>(v);
                v = dpp_add<0x140>(v);
                acc[j][b] = v;
            }
        if (kg < ROWS) {
            const int b = kg;
#pragma unroll
            for (int j = 0; j < NJ; ++j) {
                const int o = oi + 32 * j;
                if (o < NH) {
                    if (t < NT) {
                        float v = fmaxf(acc[j][b], 0.f);
                        nxt[b * KP + o] = v;
                        hidb[(size_t)t * NH + o] = v;
                    }
                } else if (o < NH + NO) {
                    lgb[b][o - NH] = acc[j][b];
                }
            }
        }
        if (do_x) *reinterpret_cast<float4*>(nxt + xb * KP + XOFF + 4 * xq) = xp;
        __syncthreads();
        if (do_e) {
            float l0 = lgb[tid][0], l1 = lgb[tid][1], l2 = lgb[tid][2];
            float s0 = l0 + g0, s1 = l1 + g1, s2 = l2 + g2;
            int am = 0; float best = s0;
            if (s1 > best) { best = s1; am = 1; }
            if (s2 > best) { am = 2; }
            size_t base = emitb + (size_t)(t - 1) * NO;
            out[base + 0] = (am == 0) ? 1.f : 0.f;
            out[base + 1] = (am == 1) ? 1.f : 0.f;
            out[base + 2] = (am == 2) ? 1.f : 0.f;
            logits[base + 0] = l0;
            logits[base + 1] = l1;
            logits[base + 2] = l2;
        }
    };
    for (int t = 0; t < NT; t += 2) {
        stepf(t,     hx[0], hx[1], lg[0]);
        stepf(t + 1, hx[1], hx[0], lg[1]);
    }
    stepf(NT, hx[0], hx[1], lg[0]);
}
}  // namespace fb

extern "C" void kernel_launch(void* const* d_in, const int* in_sizes, int n_in,
                              void* d_out, int out_size, void* d_ws, size_t ws_size,
                              hipStream_t stream) {
    const float* x   = (const float*)d_in[0];
    const float* h0  = (const float*)d_in[1];
    const float* g   = (const float*)d_in[2];
    const float* Wih = (const float*)d_in[3];
    const float* Whh = (const float*)d_in[4];
    const float* Wfc = (const float*)d_in[5];

    float* out    = (float*)d_out;
    float* hidden = out + (size_t)NB * NT * NO;
    float* logits = hidden + (size_t)NB * NT * NH;

    const size_t need = (size_t)NT * NB * NH * sizeof(float);  // 314.6 MB
    if (d_ws != nullptr && ws_size >= need) {
        float* xwbuf = (float*)d_ws;
        hipLaunchKernelGGL(xw_gemm, dim3(NB / GB, NT, (NH + GH - 1) / GH), dim3(GT),
                           0, stream, x, Wih, xwbuf);
        hipLaunchKernelGGL(rnn_rec, dim3(NB / ROWS2), dim3(NTH2), 0, stream,
                           xwbuf, h0, g, Whh, Wfc, out, hidden, logits);
    } else {
        hipLaunchKernelGGL(fb::rnn_fused, dim3(NB / fb::ROWS), dim3(fb::NTH), 0, stream,
                           x, h0, g, Wih, Whh, Wfc, out, hidden, logits);
    }
}

// Round 7
// 1557.857 us; speedup vs baseline: 1.4205x; 1.4205x over previous
//
#include <hip/hip_runtime.h>

// Problem dims (fixed by setup_inputs)
constexpr int NB = 1024;   // batch
constexpr int NT = 512;    // time steps
constexpr int NI = 100;    // input dim
constexpr int NH = 150;    // hidden dim
constexpr int NO = 3;      // output classes

// DPP-based add: v += shuffled(v).
// 0xB1 quad_perm xor1 | 0x4E quad_perm xor2 | 0x141 row_half_mirror (completes 8-sum)
// 0x140 row_mirror (completes 16-sum)
template<int CTRL>
__device__ __forceinline__ float dpp_add(float v) {
    int t = __builtin_amdgcn_update_dpp(0, __float_as_int(v), CTRL, 0xF, 0xF, true);
    return v + __int_as_float(t);
}

// Async global->LDS copy, 4B per lane: LDS dest = uniform base + lane*4.
__device__ __forceinline__ void async_copy_f32(const float* src, float* lds_dst) {
    __builtin_amdgcn_global_load_lds(
        (const __attribute__((address_space(1))) void*)src,
        (__attribute__((address_space(3))) void*)lds_dst, 4, 0, 0);
}

// ============ Kernel 1: xw[t][b][h] = sum_i x[b,t,i] * Wih[h,i]  (packed [T][B][150])
// 512 thr = 8 waves; wave w owns h in [19w, 19w+19) (152 padded, h>=150 dropped).
// W_ih staged ONCE to LDS, read wave-uniform (broadcast, conflict-free).
// x tile [64 rows][101] (stride 101: lane*101 mod 32 spans all banks -> scalar reads free).
// Output staged in LDS -> coalesced float2 stores.
constexpr int XR = 64, XTH = 512;
__global__ __launch_bounds__(XTH, 1)
void xw_gemm(const float* __restrict__ x, const float* __restrict__ Wih,
             float* __restrict__ xw)
{
    __shared__ __align__(16) float Wl[152 * NI];   // 60.8 KB
    __shared__ float xT[XR * 101];                 // 25.9 KB
    __shared__ float ot[XR * 151];                 // 38.7 KB
    const int tid = threadIdx.x;
    const int b0 = blockIdx.x * XR;
    const int t  = blockIdx.y;

    // stage W (rows 150,151 zero)
    for (int e = tid; e < 152 * 25; e += XTH) {
        int wr = e / 25, k4 = e - wr * 25;
        float4 v = make_float4(0.f, 0.f, 0.f, 0.f);
        if (wr < NH) v = *reinterpret_cast<const float4*>(Wih + (size_t)wr * NI + 4 * k4);
        *reinterpret_cast<float4*>(&Wl[wr * NI + 4 * k4]) = v;
    }
    // stage x tile (coalesced f4 global reads, scalar LDS writes at stride 101)
    for (int e = tid; e < XR * 25; e += XTH) {
        int r = e / 25, k4 = e - r * 25;
        float4 v = *reinterpret_cast<const float4*>(x + ((size_t)(b0 + r) * NT + t) * NI + 4 * k4);
        xT[r * 101 + 4 * k4 + 0] = v.x; xT[r * 101 + 4 * k4 + 1] = v.y;
        xT[r * 101 + 4 * k4 + 2] = v.z; xT[r * 101 + 4 * k4 + 3] = v.w;
    }
    __syncthreads();

    const int row = tid & 63;
    const int wv  = tid >> 6;   // 0..7
    float acc[19];
#pragma unroll
    for (int j = 0; j < 19; ++j) acc[j] = 0.f;
    const float* xr = &xT[row * 101];
    const float* wb = &Wl[19 * wv * NI];
    for (int k4 = 0; k4 < 25; ++k4) {
        const float x0 = xr[4 * k4 + 0], x1 = xr[4 * k4 + 1];
        const float x2 = xr[4 * k4 + 2], x3 = xr[4 * k4 + 3];
#pragma unroll
        for (int j = 0; j < 19; ++j) {
            const float4 w4 = *reinterpret_cast<const float4*>(&wb[j * NI + 4 * k4]); // uniform -> broadcast
            acc[j] += w4.x * x0; acc[j] += w4.y * x1;
            acc[j] += w4.z * x2; acc[j] += w4.w * x3;
        }
    }
#pragma unroll
    for (int j = 0; j < 19; ++j) {
        const int h = 19 * wv + j;
        if (h < NH) ot[row * 151 + h] = acc[j];   // stride 151: conflict-free
    }
    __syncthreads();

    // coalesced float2 stores (row stride 150 floats = 8B-aligned everywhere)
    for (int e = tid; e < XR * 75; e += XTH) {
        int r = e / 75, c2 = e - r * 75;
        float2 v = make_float2(ot[r * 151 + 2 * c2], ot[r * 151 + 2 * c2 + 1]);
        *reinterpret_cast<float2*>(&xw[((size_t)t * NB + b0 + r) * NH + 2 * c2]) = v;
    }
}

// ============ Kernel 2: recurrence h_t = relu(xw_t + h_{t-1} Whh^T), fc, gumbel-emit
// 256 thr = 4 waves, ROWS=1, grid 1024 = 4 blocks/CU (256-thr blocks are the only
// config that has co-resided; 4 independent barriers overlap latencies).
// kg = lane&7 (8 k-groups x 5 f4-chunks of K=160); oi = wv*8 + (lane>>3) in [0,32);
// o-slots o = oi+32j, j<5 (o<150 h-rows, 150..152 fc, rest dead W=0).
// Wreg = 100 floats + 5 acc ~ 115 live < 128 cap. 3-stage DPP reduce.
// xw[t+1] prefetched via global_load_lds into LDS double-buffer (0 VGPR cost).
constexpr int RTH = 256;
__global__ __launch_bounds__(RTH, 4)
void rnn_rec(const float* __restrict__ xw, const float* __restrict__ h0v,
             const float* __restrict__ g, const float* __restrict__ Whh,
             const float* __restrict__ Wfc, float* __restrict__ out,
             float* __restrict__ hidden, float* __restrict__ logits)
{
    __shared__ __align__(16) float hx[2][160];   // h + 10 zero-pad, double-buffered
    __shared__ __align__(16) float xq[2][152];   // xw stream double-buffer
    __shared__ float lg[2][4];

    const int tid = threadIdx.x, lane = tid & 63, wv = tid >> 6;
    const int kg = lane & 7, oq = lane >> 3;
    const int oi = wv * 8 + oq;        // 0..31
    const int row = blockIdx.x;

    // W slice: 5 o-slots x 5 chunks x 4 = 100 regs
    float Wreg[5][5][4];
#pragma unroll
    for (int j = 0; j < 5; ++j) {
        const int o = oi + 32 * j;
#pragma unroll
        for (int i = 0; i < 5; ++i)
#pragma unroll
            for (int q = 0; q < 4; ++q) {
                const int k = 4 * (kg + 8 * i) + q;
                float v = 0.f;
                if (k < NH) {
                    if (o < NH) v = Whh[o * NH + k];
                    else if (o < NH + NO) v = Wfc[(o - NH) * NH + k];
                }
                Wreg[j][i][q] = v;
            }
    }

    if (tid < NH) hx[0][tid] = h0v[(size_t)row * NH + tid];
    if (tid < 20) { int f = tid / 10, z = tid - 10 * (tid / 10); hx[f][NH + z] = 0.f; }
    {   // prologue: xw[0] -> xq[0]
        const float* s = xw + (size_t)row * NH;
        if (tid < 64) { async_copy_f32(s + tid, &xq[0][0]); async_copy_f32(s + 64 + tid, &xq[0][64]); }
        if (tid < 22) async_copy_f32(s + 128 + tid, &xq[0][128]);
    }
    __syncthreads();

    float* hidb = hidden + (size_t)row * NT * NH;
    const float* gb = g + (size_t)row * NT * NO;
    float* ob = out + (size_t)row * NT * NO;
    float* lb = logits + (size_t)row * NT * NO;

    auto stepf = [&](int t, const float* __restrict__ cur, float* __restrict__ nxt,
                     float* __restrict__ lgc, const float* __restrict__ xv,
                     float* __restrict__ xnxt) {
        // issue async prefetch of xw[t+1] (full step of slack before barrier drain)
        if (t + 1 < NT) {
            const float* s = xw + ((size_t)(t + 1) * NB + row) * NH;
            if (tid < 64) { async_copy_f32(s + tid, xnxt); async_copy_f32(s + 64 + tid, xnxt + 64); }
            if (tid < 22) async_copy_f32(s + 128 + tid, xnxt + 128);
        }
        // partial dots over this thread's 5 chunks
        float acc[5];
#pragma unroll
        for (int j = 0; j < 5; ++j) acc[j] = 0.f;
        const float4* c4 = reinterpret_cast<const float4*>(cur);
#pragma unroll
        for (int i = 0; i < 5; ++i) {
            const float4 hv = c4[kg + 8 * i];   // 8 distinct addrs, broadcast to oq: conflict-free
#pragma unroll
            for (int j = 0; j < 5; ++j) {
                acc[j] += Wreg[j][i][0] * hv.x; acc[j] += Wreg[j][i][1] * hv.y;
                acc[j] += Wreg[j][i][2] * hv.z; acc[j] += Wreg[j][i][3] * hv.w;
            }
        }
        // 3-stage DPP butterfly across the 8 k-groups
#pragma unroll
        for (int j = 0; j < 5; ++j) {
            float v = acc[j];
            v = dpp_add<0xB1>(v); v = dpp_add<0x4E>(v); v = dpp_add<0x141>(v);
            acc[j] = v;
        }
        // phase B: kg==0 lanes write their 5 o-slots
        if (kg == 0) {
#pragma unroll
            for (int j = 0; j < 5; ++j) {
                const int o = oi + 32 * j;
                if (o < NH) {
                    if (t < NT) {
                        float v = fmaxf(acc[j] + xv[o], 0.f);
                        nxt[o] = v;
                        hidb[(size_t)t * NH + o] = v;
                    }
                } else if (o < NH + NO) lgc[o - NH] = acc[j];
            }
        }
        __syncthreads();   // drains prefetch (vmcnt) + hx/lg writes
        // emit out/logits for time t-1
        if (tid == 0 && t >= 1) {
            float l0 = lgc[0], l1 = lgc[1], l2 = lgc[2];
            const float* gp = gb + (size_t)(t - 1) * NO;
            float s0 = l0 + gp[0], s1 = l1 + gp[1], s2 = l2 + gp[2];
            int am = 0; float best = s0;
            if (s1 > best) { best = s1; am = 1; }
            if (s2 > best) am = 2;
            size_t base = (size_t)(t - 1) * NO;
            ob[base + 0] = (am == 0) ? 1.f : 0.f;
            ob[base + 1] = (am == 1) ? 1.f : 0.f;
            ob[base + 2] = (am == 2) ? 1.f : 0.f;
            lb[base + 0] = l0; lb[base + 1] = l1; lb[base + 2] = l2;
        }
    };

    for (int t = 0; t < NT; t += 2) {
        stepf(t,     hx[0], hx[1], lg[0], xq[0], xq[1]);
        stepf(t + 1, hx[1], hx[0], lg[1], xq[1], xq[0]);
    }
    stepf(NT, hx[0], hx[1], lg[0], xq[0], xq[1]);  // tail: fc of h[NT-1] + final emit
}

// ============ Fallback (R5 fused kernel verbatim) if d_ws is too small ============
namespace fb {
constexpr int KP = 256, XOFF = 152, ROWS = 2, KG = 16, NCH = 4, NJ = 5, NTH = 512;
__global__ __launch_bounds__(NTH, 2)
void rnn_fused(const float* __restrict__ x, const float* __restrict__ h0,
               const float* __restrict__ g, const float* __restrict__ Wih,
               const float* __restrict__ Whh, const float* __restrict__ Wfc,
               float* __restrict__ out, float* __restrict__ hidden,
               float* __restrict__ logits)
{
    __shared__ __align__(16) float hx[2][ROWS * KP];
    __shared__ float lg[2][ROWS][4];
    const int tid = threadIdx.x, lane = tid & 63, wv = tid >> 6;
    const int kg = lane & 15, oq = lane >> 4, oi = wv * 4 + oq;
    const int row0 = blockIdx.x * ROWS;
    float Wreg[NJ][NCH][4];
#pragma unroll
    for (int j = 0; j < NJ; ++j) {
        const int o = oi + 32 * j;
#pragma unroll
        for (int i = 0; i < NCH; ++i)
#pragma unroll
            for (int q = 0; q < 4; ++q) {
                const int k = 4 * (kg + KG * i) + q;
                float v = 0.f;
                if (o < NH) {
                    if (k < NH) v = Whh[o * NH + k];
                    else if (k >= XOFF && k < XOFF + NI) v = Wih[o * NI + (k - XOFF)];
                } else if (o < NH + NO) {
                    if (k < NH) v = Wfc[(o - NH) * NH + k];
                }
                Wreg[j][i][q] = v;
            }
    }
    for (int e = tid; e < ROWS * NH; e += NTH) {
        int b = e / NH, k = e - b * NH;
        hx[0][b * KP + k] = h0[(row0 + b) * NH + k];
    }
    for (int e = tid; e < ROWS * NI; e += NTH) {
        int b = e / NI, i = e - b * NI;
        hx[0][b * KP + XOFF + i] = x[((size_t)(row0 + b) * NT + 0) * NI + i];
    }
    if (tid < 2 * ROWS * 6) {
        int u = tid; int f = u / (ROWS * 6); u -= f * (ROWS * 6);
        int b = u / 6, z = u - b * 6;
        int k = (z < 2) ? (NH + z) : (252 + z - 2);
        hx[f][b * KP + k] = 0.f;
    }
    __syncthreads();
    const int xb = (tid / 25) & 1, xq = tid - (tid / 25) * 25;
    const float* xrow = x + ((size_t)(row0 + xb) * NT) * NI + 4 * xq;
    float* hidb = hidden + ((size_t)(row0 + (kg & 1)) * NT) * NH;
    const float* grow = g + ((size_t)(row0 + (tid & 1)) * NT) * NO;
    const size_t emitb = ((size_t)(row0 + (tid & 1)) * NT) * NO;
    auto stepf = [&](int t, const float* __restrict__ cur, float* __restrict__ nxt,
                     float (*__restrict__ lgb)[4]) {
        float4 xp = make_float4(0.f, 0.f, 0.f, 0.f);
        const bool do_x = (tid < 50) && (t < NT - 1);
        if (do_x) xp = *reinterpret_cast<const float4*>(xrow + (size_t)(t + 1) * NI);
        float g0 = 0.f, g1 = 0.f, g2 = 0.f;
        const bool do_e = (tid < ROWS) && (t >= 1);
        if (do_e) {
            const float* gp = grow + (size_t)(t - 1) * NO;
            g0 = gp[0]; g1 = gp[1]; g2 = gp[2];
        }
        const float4* cur4 = reinterpret_cast<const float4*>(cur) + kg;
        float acc[NJ][ROWS];
#pragma unroll
        for (int j = 0; j < NJ; ++j)
#pragma unroll
            for (int b = 0; b < ROWS; ++b) acc[j][b] = 0.f;
#pragma unroll
        for (int i = 0; i < NCH; ++i)
#pragma unroll
            for (int b = 0; b < ROWS; ++b) {
                const float4 hv = cur4[b * (KP / 4) + KG * i];
#pragma unroll
                for (int j = 0; j < NJ; ++j) {
                    acc[j][b] += Wreg[j][i][0] * hv.x;
                    acc[j][b] += Wreg[j][i][1] * hv.y;
                    acc[j][b] += Wreg[j][i][2] * hv.z;
                    acc[j][b] += Wreg[j][i][3] * hv.w;
                }
            }
#pragma unroll
        for (int j = 0; j < NJ; ++j)
#pragma unroll
            for (int b = 0; b < ROWS; ++b) {
                float v = acc[j][b];
                v = dpp_add<0xB1>(v); v = dpp_add<0x4E>(v);
                v = dpp_add<0x141>(v); v = dpp_add<0x140>(v);
                acc[j][b] = v;
            }
        if (kg < ROWS) {
            const int b = kg;
#pragma unroll
            for (int j = 0; j < NJ; ++j) {
                const int o = oi + 32 * j;
                if (o < NH) {
                    if (t < NT) {
                        float v = fmaxf(acc[j][b], 0.f);
                        nxt[b * KP + o] = v;
                        hidb[(size_t)t * NH + o] = v;
                    }
                } else if (o < NH + NO) {
                    lgb[b][o - NH] = acc[j][b];
                }
            }
        }
        if (do_x) *reinterpret_cast<float4*>(nxt + xb * KP + XOFF + 4 * xq) = xp;
        __syncthreads();
        if (do_e) {
            float l0 = lgb[tid][0], l1 = lgb[tid][1], l2 = lgb[tid][2];
            float s0 = l0 + g0, s1 = l1 + g1, s2 = l2 + g2;
            int am = 0; float best = s0;
            if (s1 > best) { best = s1; am = 1; }
            if (s2 > best) { am = 2; }
            size_t base = emitb + (size_t)(t - 1) * NO;
            out[base + 0] = (am == 0) ? 1.f : 0.f;
            out[base + 1] = (am == 1) ? 1.f : 0.f;
            out[base + 2] = (am == 2) ? 1.f : 0.f;
            logits[base + 0] = l0;
            logits[base + 1] = l1;
            logits[base + 2] = l2;
        }
    };
    for (int t = 0; t < NT; t += 2) {
        stepf(t,     hx[0], hx[1], lg[0]);
        stepf(t + 1, hx[1], hx[0], lg[1]);
    }
    stepf(NT, hx[0], hx[1], lg[0]);
}
}  // namespace fb

extern "C" void kernel_launch(void* const* d_in, const int* in_sizes, int n_in,
                              void* d_out, int out_size, void* d_ws, size_t ws_size,
                              hipStream_t stream) {
    const float* x   = (const float*)d_in[0];
    const float* h0  = (const float*)d_in[1];
    const float* g   = (const float*)d_in[2];
    const float* Wih = (const float*)d_in[3];
    const float* Whh = (const float*)d_in[4];
    const float* Wfc = (const float*)d_in[5];

    float* out    = (float*)d_out;
    float* hidden = out + (size_t)NB * NT * NO;
    float* logits = hidden + (size_t)NB * NT * NH;

    const size_t need = (size_t)NT * NB * NH * sizeof(float);  // 314.6 MB (R6-proven)
    if (d_ws != nullptr && ws_size >= need) {
        float* xwbuf = (float*)d_ws;
        hipLaunchKernelGGL(xw_gemm, dim3(NB / XR, NT), dim3(XTH), 0, stream,
                           x, Wih, xwbuf);
        hipLaunchKernelGGL(rnn_rec, dim3(NB), dim3(RTH), 0, stream,
                           xwbuf, h0, g, Whh, Wfc, out, hidden, logits);
    } else {
        hipLaunchKernelGGL(fb::rnn_fused, dim3(NB / fb::ROWS), dim3(fb::NTH), 0, stream,
                           x, h0, g, Wih, Whh, Wfc, out, hidden, logits);
    }
}